// Round 11
// baseline (194.239 us; speedup 1.0000x reference)
//
#include <hip/hip_runtime.h>

// Path signature depth 5, d=10, L=128, B=256 — MFMA, fused produce/consume.
// Base = round-9 kernel (103.6 µs, PASSED, absmax 8.0). ONE change:
//   * For scan threads (tid<250), produce() runs BEFORE the fragment loads.
//     Previously the 18 fragment ds_reads were issued first, queueing the
//     scan's 12 source reads ~200-400 cyc behind them on the CU's LDS pipe
//     and delaying the serial scan chain (the per-chunk long pole) every
//     chunk. Non-scan threads keep loads-first (their MFMA wants operands
//     early). Pure intra-thread code motion: no sync, geometry, or numeric
//     change. Discriminating probe: Δ>4% => scan is queue/latency-bound;
//     Δ≈0 => issue-bound (then: v_pk_fma packing next).
// NOTE (empirical, rounds 4/6/7/10): any deviation from this 8-wave/512-thr
// symmetric structure (wave-count, tile ownership, buffer scheme, VGPR caps)
// has failed correctness non-deterministically. Do not touch geometry.
//
// Structure: per batch a [1000 x 254] x [254 x 110] GEMM (K = 2 terms per
// segment: W1*d[c4]*R[e] + W0h*d[c4]*d[e]; level-4 rides as aug cols
// 100..109), fp32 accuracy via 2-way bf16 split, 3 cross terms (al*bl
// dropped: measured absmax 8.0 vs threshold 33.6). A/B double-buffered,
// ONE barrier per chunk, 4 blocks/batch (q = 250-row slice), 1 block/CU.

#define D10    10
#define LPATH  128
#define NSEG   127
#define BLOCK  512
#define NROW   256     // panel rows per block (250 active)
#define NROWA  250
#define NCOL   112     // 100 level5 cols + 10 level4-aug + 2 pad
#define NCOLA  110
#define KC     16      // segments per chunk -> K = 32 bf16
#define NCH    8       // 8*16 = 128 >= 127 (u=127 zero pad)
#define SD     132     // dTT/RT row stride (floats)
#define OUT_PER_B 111110

typedef __attribute__((ext_vector_type(8))) short bf16x8;
typedef __attribute__((ext_vector_type(4))) float f32x4;

// pack bf16(x),bf16(y) (truncation) into hi word; packed residuals into lo.
__device__ __forceinline__ unsigned pack_split(float x, float y, unsigned &lo)
{
    unsigned xb = __float_as_uint(x), yb = __float_as_uint(y);
    float xr = x - __uint_as_float(xb & 0xffff0000u);
    float yr = y - __uint_as_float(yb & 0xffff0000u);
    lo = (__float_as_uint(xr) >> 16) | (__float_as_uint(yr) & 0xffff0000u);
    return (xb >> 16) | (yb & 0xffff0000u);
}

__global__ __launch_bounds__(BLOCK, 1) void sig_kernel(
        const float* __restrict__ path,   // [B][D10][LPATH]
        float* __restrict__ out)          // [B][OUT_PER_B]
{
    __shared__ __align__(16) float dTT[D10 * SD];          // d_u[c]
    __shared__ __align__(16) float RT [D10 * SD];          // R_u[c] suffix
    __shared__ __align__(16) short AhiS[2][4 * NROW * 8];  // [buf][kg][row][8]
    __shared__ __align__(16) short AloS[2][4 * NROW * 8];
    __shared__ __align__(16) short BhiS[2][4 * NCOL * 8];  // [buf][kg][col][8]
    __shared__ __align__(16) short BloS[2][4 * NCOL * 8];

    const int tid = threadIdx.x;
    const int bb  = blockIdx.x;
    const int b   = bb >> 2;
    const int q   = bb & 3;                 // 250-row slice of the 1000 rows
    const float* pb = path + (size_t)b * (D10 * LPATH);

    // ---- delta + suffix tables (R telescopes; t>=NSEG zero-padded) ----
    for (int idx = tid; idx < D10 * SD; idx += BLOCK) {
        int c = idx / SD, t = idx - c * SD;
        float d = 0.f, r = 0.f;
        if (t < NSEG) {
            float p1 = pb[c * LPATH + t + 1];
            d = p1 - pb[c * LPATH + t];
            r = pb[c * LPATH + NSEG] - p1;
        }
        dTT[idx] = d;
        RT [idx] = r;
    }
    // zero pad A rows 250..255 (both buffers, all k-groups) once
    for (int idx = tid; idx < 2 * 4 * (NROW - NROWA) * 8; idx += BLOCK) {
        int bufi = idx / (4 * 6 * 8);
        int rem  = idx - bufi * (4 * 6 * 8);
        int kg   = rem / (6 * 8);
        int rr   = rem - kg * (6 * 8);
        int o = (kg * NROW + NROWA) * 8 + rr;
        AhiS[bufi][o] = 0; AloS[bufi][o] = 0;
    }
    // zero pad B cols 110..111 (both buffers) once
    if (tid < 2 * 4 * 2 * 8) {
        int bufi = tid >> 6;
        int rem  = tid & 63;
        int kg   = rem >> 4;
        int rr   = rem & 15;
        int o = (kg * NCOL + NCOLA) * 8 + rr;
        BhiS[bufi][o] = 0; BloS[bufi][o] = 0;
    }

    // ---- scan identity (threads < 250): row = q*250 + tid ----
    const int grow = q * NROWA + tid;
    const int g   = grow / 100;
    const int m3  = grow - g * 100;
    const int c2  = m3 / 10;
    const int c3  = m3 - c2 * 10;
    const int goff = g * SD, c2off = c2 * SD, c3off = c3 * SD;

    const int lane = tid & 63;
    const int wv   = tid >> 6;      // 8 waves x 32 rows each
    const int rl   = lane & 15;
    const int kgl  = lane >> 4;

    float s1 = 0.f, s2 = 0.f, s3 = 0.f;
    f32x4 acc[2][7];
#pragma unroll
    for (int i = 0; i < 2; ++i)
#pragma unroll
        for (int nt = 0; nt < 7; ++nt) acc[i][nt] = f32x4{0.f, 0.f, 0.f, 0.f};

    // scan part of produce (tid<250 only): serial chain, the long pole.
    auto produceScan = [&](int pp, int kc0) {
#pragma unroll
        for (int w0 = 0; w0 < KC; w0 += 4) {
            float4 g4 = *(const float4*)&dTT[goff  + kc0 + w0];
            float4 a4 = *(const float4*)&dTT[c2off + kc0 + w0];
            float4 b4 = *(const float4*)&dTT[c3off + kc0 + w0];
            float ga[4] = {g4.x, g4.y, g4.z, g4.w};
            float aa[4] = {a4.x, a4.y, a4.z, a4.w};
            float ba[4] = {b4.x, b4.y, b4.z, b4.w};
            unsigned hw[4], lw[4];
#pragma unroll
            for (int j = 0; j < 4; ++j) {
                float dg = ga[j], d2 = aa[j], d3 = ba[j];
                float u24 = s2 + (s1 + dg * 0.25f)     * d2 * (1.f / 3.f);
                float u25 = s2 + (s1 + dg * 0.2f)      * d2 * 0.25f;
                float u23 = s2 + (s1 + dg * (1.f/3.f)) * d2 * 0.5f;
                float w1v = s3 + u24 * d3 * 0.5f;
                float w0h = 0.5f * (s3 + u25 * d3 * (1.f / 3.f));
                s3 += u23 * d3;
                s2 += (s1 + dg * 0.5f) * d2;
                s1 += dg;                     // d=0 pads leave state fixed
                hw[j] = pack_split(w1v, w0h, lw[j]);  // k=2u: W1, 2u+1: W0h
            }
            const int ai = ((w0 >> 2) * NROW + tid) * 8;
            *(uint4*)&AhiS[pp][ai] = make_uint4(hw[0], hw[1], hw[2], hw[3]);
            *(uint4*)&AloS[pp][ai] = make_uint4(lw[0], lw[1], lw[2], lw[3]);
        }
    };
    // B-build part of produce (tid>=256 only).
    auto produceB = [&](int pp, int kc0) {
        for (int s = tid - 256; s < 4 * NCOLA; s += 256) {
            const int cb  = s >> 2;         // col 0..109
            const int kgB = s & 3;
            int c4o, ebo = 0;
            if (cb < 100) { int c4 = cb / 10; ebo = (cb - c4 * 10) * SD; c4o = c4 * SD; }
            else          { c4o = (cb - 100) * SD; }
            const int u0 = kc0 + kgB * 4;
            float4 d4 = *(const float4*)&dTT[c4o + u0];
            float da[4] = {d4.x, d4.y, d4.z, d4.w};
            unsigned hw[4], lw[4];
            if (cb < 100) {
                float4 e4 = *(const float4*)&dTT[ebo + u0];
                float4 r4 = *(const float4*)&RT [ebo + u0];
                float ea[4] = {e4.x, e4.y, e4.z, e4.w};
                float ra[4] = {r4.x, r4.y, r4.z, r4.w};
#pragma unroll
                for (int j = 0; j < 4; ++j)
                    hw[j] = pack_split(da[j] * ra[j], da[j] * ea[j], lw[j]);
            } else {        // level-4 aug cols: B1 = d, B0 = 0
#pragma unroll
                for (int j = 0; j < 4; ++j)
                    hw[j] = pack_split(da[j], 0.f, lw[j]);
            }
            const int bi = (kgB * NCOL + cb) * 8;
            *(uint4*)&BhiS[pp][bi] = make_uint4(hw[0], hw[1], hw[2], hw[3]);
            *(uint4*)&BloS[pp][bi] = make_uint4(lw[0], lw[1], lw[2], lw[3]);
        }
    };

    __syncthreads();                 // tables + pads ready
    if (tid < NROWA) produceScan(0, 0);
    else if (tid >= 256) produceB(0, 0);
    __syncthreads();                 // buf0 ready

    for (int ch = 0; ch < NCH; ++ch) {
        const int p = ch & 1;
        bf16x8 bh[7], bl[7];
        bf16x8 ah[2], al[2];
        if (tid < NROWA) {
            // ---- scan threads: produce FIRST (serial chain starts with no
            //      LDS-queue delay), fragment loads after ----
            if (ch + 1 < NCH) produceScan(p ^ 1, (ch + 1) * KC);
#pragma unroll
            for (int nt = 0; nt < 7; ++nt) {
                const int bi = (kgl * NCOL + nt * 16 + rl) * 8;
                bh[nt] = *(const bf16x8*)&BhiS[p][bi];
                bl[nt] = *(const bf16x8*)&BloS[p][bi];
            }
#pragma unroll
            for (int i = 0; i < 2; ++i) {
                const int ai = (kgl * NROW + wv * 32 + i * 16 + rl) * 8;
                ah[i] = *(const bf16x8*)&AhiS[p][ai];
                al[i] = *(const bf16x8*)&AloS[p][ai];
            }
        } else {
            // ---- non-scan threads: loads first (feed MFMA early), then
            //      B-build for chunk ch+1 ----
#pragma unroll
            for (int nt = 0; nt < 7; ++nt) {
                const int bi = (kgl * NCOL + nt * 16 + rl) * 8;
                bh[nt] = *(const bf16x8*)&BhiS[p][bi];
                bl[nt] = *(const bf16x8*)&BloS[p][bi];
            }
#pragma unroll
            for (int i = 0; i < 2; ++i) {
                const int ai = (kgl * NROW + wv * 32 + i * 16 + rl) * 8;
                ah[i] = *(const bf16x8*)&AhiS[p][ai];
                al[i] = *(const bf16x8*)&AloS[p][ai];
            }
            if (ch + 1 < NCH && tid >= 256) produceB(p ^ 1, (ch + 1) * KC);
        }
        // ---- 2 M-tiles x 7 N-tiles x 3 split-term MFMAs ----
#pragma unroll
        for (int i = 0; i < 2; ++i)
#pragma unroll
            for (int nt = 0; nt < 7; ++nt) {
                acc[i][nt] = __builtin_amdgcn_mfma_f32_16x16x32_bf16(ah[i], bh[nt], acc[i][nt], 0, 0, 0);
                acc[i][nt] = __builtin_amdgcn_mfma_f32_16x16x32_bf16(ah[i], bl[nt], acc[i][nt], 0, 0, 0);
                acc[i][nt] = __builtin_amdgcn_mfma_f32_16x16x32_bf16(al[i], bh[nt], acc[i][nt], 0, 0, 0);
            }
        __syncthreads();             // buf[p^1] written; buf[p] reads done
    }

    // ---- epilogue (registers only; no barrier) ----
    float* ob = out + (size_t)b * OUT_PER_B;
    if (tid < NROWA) {
        ob[110 + grow] = s3;                       // level 3
        if (c3 == 0) ob[10 + g * 10 + c2] = s2;    // level 2
        if (m3 == 0) ob[g] = s1;                   // level 1
    }
    // D layout (m89-verified): col = lane&15, row = (lane>>4)*4 + reg
#pragma unroll
    for (int i = 0; i < 2; ++i) {
#pragma unroll
        for (int r = 0; r < 4; ++r) {
            const int prow = wv * 32 + i * 16 + kgl * 4 + r;
            if (prow < NROWA) {
                const int gr = q * NROWA + prow;
#pragma unroll
                for (int nt = 0; nt < 7; ++nt) {
                    const int col = nt * 16 + rl;
                    const float v = acc[i][nt][r];
                    if (col < 100)
                        ob[11110 + (size_t)gr * 100 + col] = v;   // level 5
                    else if (col < NCOLA)
                        ob[1110 + gr * 10 + (col - 100)] = v;     // level 4
                }
            }
        }
    }
}

extern "C" void kernel_launch(void* const* d_in, const int* in_sizes, int n_in,
                              void* d_out, int out_size, void* d_ws, size_t ws_size,
                              hipStream_t stream) {
    const float* path = (const float*)d_in[0];
    float* out = (float*)d_out;
    int B = in_sizes[0] / (D10 * LPATH);   // 256
    sig_kernel<<<B * 4, BLOCK, 0, stream>>>(path, out);
}